// Round 13
// baseline (575.529 us; speedup 1.0000x reference)
//
#include <hip/hip_runtime.h>
#include <hip/hip_bf16.h>

// Sizes
constexpr int BATCH = 8192;
constexpr int NREAL = 2000;   // real feature / output-col count
constexpr int KSLOT = 2048;   // per-matrix padded K slot
constexpr int KPAD  = 6144;   // 3 * 2048
constexpr int NPAD  = 2048;   // padded N
constexpr int NT    = KPAD / 64;  // 96 K-tiles of 64

typedef short bf16x8 __attribute__((ext_vector_type(8)));
typedef float f32x4  __attribute__((ext_vector_type(4)));

__device__ inline void gload_lds16(const void* g, void* l) {
  __builtin_amdgcn_global_load_lds(
      (const __attribute__((address_space(1))) unsigned int*)g,
      (__attribute__((address_space(3))) unsigned int*)l,
      16, 0, 0);
}

__device__ inline unsigned short f2bf(float x) {
  union { float f; unsigned int u; } v;
  v.f = x;
  unsigned int r = v.u + 0x7fffu + ((v.u >> 16) & 1u);
  return (unsigned short)(r >> 16);
}

// ---------------------------------------------------------------------------
// Kernel 1: standardize (ddof=1) activations into A_cat [8192][6144] bf16.
// grid (8192, 3), block 256.
// ---------------------------------------------------------------------------
__global__ __launch_bounds__(256) void apack_kernel(
    const float* __restrict__ prev, const float* __restrict__ nxt,
    const float* __restrict__ selfa, unsigned short* __restrict__ Acat) {
  __shared__ float red[4];
  const int row = blockIdx.x;
  const int mat = blockIdx.y;
  const float* src = (mat == 0) ? prev : (mat == 1) ? nxt : selfa;
  const int t = threadIdx.x;

  float x[8];
  float s1 = 0.f;
  if (t < 250) {
    const float4* p = (const float4*)(src + (size_t)row * NREAL + t * 8);
    float4 a = p[0], b = p[1];
    x[0] = a.x; x[1] = a.y; x[2] = a.z; x[3] = a.w;
    x[4] = b.x; x[5] = b.y; x[6] = b.z; x[7] = b.w;
#pragma unroll
    for (int j = 0; j < 8; ++j) s1 += x[j];
  } else {
#pragma unroll
    for (int j = 0; j < 8; ++j) x[j] = 0.f;
  }
#pragma unroll
  for (int o = 32; o; o >>= 1) s1 += __shfl_xor(s1, o);
  if ((t & 63) == 0) red[t >> 6] = s1;
  __syncthreads();
  const float mean = (red[0] + red[1] + red[2] + red[3]) * (1.f / 2000.f);
  __syncthreads();

  float ss = 0.f;
  if (t < 250) {
#pragma unroll
    for (int j = 0; j < 8; ++j) { float d = x[j] - mean; ss += d * d; }
  }
#pragma unroll
  for (int o = 32; o; o >>= 1) ss += __shfl_xor(ss, o);
  if ((t & 63) == 0) red[t >> 6] = ss;
  __syncthreads();
  const float var = (red[0] + red[1] + red[2] + red[3]) * (1.f / 1999.f);
  const float scale = 1.f / (sqrtf(var) + 1e-8f);

  unsigned short o8[8];
  if (t < 250) {
#pragma unroll
    for (int j = 0; j < 8; ++j) o8[j] = f2bf((x[j] - mean) * scale);
  } else {
#pragma unroll
    for (int j = 0; j < 8; ++j) o8[j] = 0;
  }
  uint4 q;
  q.x = (unsigned)o8[0] | ((unsigned)o8[1] << 16);
  q.y = (unsigned)o8[2] | ((unsigned)o8[3] << 16);
  q.z = (unsigned)o8[4] | ((unsigned)o8[5] << 16);
  q.w = (unsigned)o8[6] | ((unsigned)o8[7] << 16);
  *(uint4*)(Acat + (size_t)row * KPAD + mat * KSLOT + t * 8) = q;
}

// ---------------------------------------------------------------------------
// Kernel 2: weight transpose-pack into fragment-ordered W_fr (R12-validated).
// Slot (cb16, k32) = 1KB: lane l holds W[col=cb16*16+(l&15)]
// [k = k32*32 + (l>>4)*8 .. +8]. grid (128, 3), block 256.
// ---------------------------------------------------------------------------
__global__ __launch_bounds__(256) void wfrag_kernel(
    const float* __restrict__ fW, const float* __restrict__ bW,
    const float* __restrict__ lW, unsigned short* __restrict__ Wfr) {
  __shared__ unsigned short tile[16][520];
  const int cb16 = blockIdx.x;
  const int m = blockIdx.y;
  const float* src = (m == 0) ? fW : (m == 1) ? bW : lW;
  const int t = threadIdx.x;
  const int r = t >> 4;
  const int c = t & 15;
  const int s = cb16 * 16 + r;
  const bool rowok = (s < NREAL);

  for (int kc0 = 0; kc0 < KSLOT; kc0 += 512) {
#pragma unroll
    for (int v = 0; v < 8; ++v) {
      const int k = kc0 + c * 32 + v * 4;
      float4 f = make_float4(0.f, 0.f, 0.f, 0.f);
      if (rowok && k < NREAL)
        f = *(const float4*)(src + (size_t)s * NREAL + k);
      tile[r][c * 32 + v * 4 + 0] = f2bf(f.x);
      tile[r][c * 32 + v * 4 + 1] = f2bf(f.y);
      tile[r][c * 32 + v * 4 + 2] = f2bf(f.z);
      tile[r][c * 32 + v * 4 + 3] = f2bf(f.w);
    }
    __syncthreads();
#pragma unroll
    for (int w = 0; w < 4; ++w) {
      const int slot = w * 4 + (t >> 6);
      const int lane = t & 63;
      const uint4 q = *(const uint4*)&tile[lane & 15][slot * 32 + (lane >> 4) * 8];
      *(uint4*)(Wfr + ((size_t)(cb16 * 192 + m * 64 + (kc0 >> 5) + slot) * 512)
                + lane * 8) = q;
    }
    __syncthreads();
  }
}

// ---------------------------------------------------------------------------
// Kernel 3: 256x256 bf16 GEMM, 16x16x32 MFMA, 8 waves (2M x 4N), 128x64/wave.
// B direct-from-global (Wfr, reg ping-pong bcA/bcB, loaded 1 tile ahead);
// A via LDS, TRIPLE-buffered 96 KB, staged 2 tiles ahead; af PRE-READ into
// regs per m-half quadrant (8 b128) before each 32-MFMA cluster (R9 lesson:
// inline reads cost ~8pts MfmaUtil). ONE counted vmcnt(4) + ONE barrier per
// tile: steady FIFO [A(t+2)x4, B(t+2)x8, A(t+3)x4] -> gate forces exactly
// t+2's A+B (issued 1-2 tiles = ~5000cy back). LDS pipe/tile ~1800cy <
// MFMA 2480cy/SIMD. 6-tile unroll keeps buf/reg indices static.
// grid 256 (= 32 bm x 8 bn), block 512.
// ---------------------------------------------------------------------------
__global__ __launch_bounds__(512, 2) void gemm_kernel(
    const unsigned short* __restrict__ A,    // [8192][6144] bf16
    const unsigned short* __restrict__ Wfr,  // fragment-packed weights
    const float* __restrict__ fb, const float* __restrict__ bb,
    const float* __restrict__ lb,
    const float* __restrict__ selfact,       // [8192][2000] f32
    float* __restrict__ out) {               // [8192][2000] f32
  __shared__ unsigned short ldsA[3][2][8192];   // [buf][kq] 96 KiB
  unsigned short* ldsF = &ldsA[0][0][0];

  const int tid  = threadIdx.x;
  const int wave = tid >> 6;
  const int lane = tid & 63;
  const int wm = wave >> 2;     // 0..1
  const int wn = wave & 3;      // 0..3

  // XCD-aware block swizzle
  const int nbid = (blockIdx.x & 7) * 32 + (blockIdx.x >> 3);
  const int bm = nbid >> 3;     // 0..31
  const int bn = nbid & 7;      // 0..7

  // A staging source (R9 decode, 0-conflict proven)
  const int srow = tid >> 2;
  const int sc = (tid & 3) ^ ((tid >> 3) & 3);
  const unsigned short* Asrc =
      A + (size_t)(bm * 256 + srow) * KPAD + sc * 8;

  // A fragment read base (R9)
  const int pcx = (lane >> 4) ^ ((lane >> 1) & 3);
  const unsigned short* aF = ldsF + (wm * 128 + (lane & 15)) * 32 + pcx * 8;

  // B fragment global base: cb16 = bn*16 + wn*4 + fn
  const unsigned short* Bbase =
      Wfr + (size_t)(bn * 16 + wn * 4) * 192 * 512 + lane * 8;

  f32x4 acc[8][4] = {};
  bf16x8 bcA[4][2], bcB[4][2];

#define STQ(bu, kq, rh, tt) \
    gload_lds16(Asrc + (size_t)(rh) * 128 * KPAD + (size_t)(tt) * 64 + (kq) * 32, \
                ldsF + ((bu) * 2 + (kq)) * 8192 + (rh) * 4096 + wave * 512);
#define STAGE_A(bu, tt) { \
    STQ(bu, 0, 0, tt) STQ(bu, 0, 1, tt) STQ(bu, 1, 0, tt) STQ(bu, 1, 1, tt) }

#define LOADB(dst, tt) \
    _Pragma("unroll") for (int fn = 0; fn < 4; ++fn) \
    _Pragma("unroll") for (int kq = 0; kq < 2; ++kq) \
      dst[fn][kq] = *(const bf16x8*)(Bbase + (size_t)fn * 98304 + \
          ((size_t)(tt) * 2 + kq) * 512);

  // per m-half: pre-read 8 af b128, then 32-MFMA cluster
#define COMPUTE(bu, bcur) \
    _Pragma("unroll") for (int mh = 0; mh < 2; ++mh) { \
      bf16x8 af0k0 = *(const bf16x8*)(aF + ((bu) * 2 + 0) * 8192 + (mh * 4 + 0) * 512); \
      bf16x8 af1k0 = *(const bf16x8*)(aF + ((bu) * 2 + 0) * 8192 + (mh * 4 + 1) * 512); \
      bf16x8 af2k0 = *(const bf16x8*)(aF + ((bu) * 2 + 0) * 8192 + (mh * 4 + 2) * 512); \
      bf16x8 af3k0 = *(const bf16x8*)(aF + ((bu) * 2 + 0) * 8192 + (mh * 4 + 3) * 512); \
      bf16x8 af0k1 = *(const bf16x8*)(aF + ((bu) * 2 + 1) * 8192 + (mh * 4 + 0) * 512); \
      bf16x8 af1k1 = *(const bf16x8*)(aF + ((bu) * 2 + 1) * 8192 + (mh * 4 + 1) * 512); \
      bf16x8 af2k1 = *(const bf16x8*)(aF + ((bu) * 2 + 1) * 8192 + (mh * 4 + 2) * 512); \
      bf16x8 af3k1 = *(const bf16x8*)(aF + ((bu) * 2 + 1) * 8192 + (mh * 4 + 3) * 512); \
      __builtin_amdgcn_s_setprio(1); \
      _Pragma("unroll") for (int fn = 0; fn < 4; ++fn) { \
        acc[mh * 4 + 0][fn] = __builtin_amdgcn_mfma_f32_16x16x32_bf16(af0k0, bcur[fn][0], acc[mh * 4 + 0][fn], 0, 0, 0); \
        acc[mh * 4 + 1][fn] = __builtin_amdgcn_mfma_f32_16x16x32_bf16(af1k0, bcur[fn][0], acc[mh * 4 + 1][fn], 0, 0, 0); \
        acc[mh * 4 + 2][fn] = __builtin_amdgcn_mfma_f32_16x16x32_bf16(af2k0, bcur[fn][0], acc[mh * 4 + 2][fn], 0, 0, 0); \
        acc[mh * 4 + 3][fn] = __builtin_amdgcn_mfma_f32_16x16x32_bf16(af3k0, bcur[fn][0], acc[mh * 4 + 3][fn], 0, 0, 0); \
        acc[mh * 4 + 0][fn] = __builtin_amdgcn_mfma_f32_16x16x32_bf16(af0k1, bcur[fn][1], acc[mh * 4 + 0][fn], 0, 0, 0); \
        acc[mh * 4 + 1][fn] = __builtin_amdgcn_mfma_f32_16x16x32_bf16(af1k1, bcur[fn][1], acc[mh * 4 + 1][fn], 0, 0, 0); \
        acc[mh * 4 + 2][fn] = __builtin_amdgcn_mfma_f32_16x16x32_bf16(af2k1, bcur[fn][1], acc[mh * 4 + 2][fn], 0, 0, 0); \
        acc[mh * 4 + 3][fn] = __builtin_amdgcn_mfma_f32_16x16x32_bf16(af3k1, bcur[fn][1], acc[mh * 4 + 3][fn], 0, 0, 0); \
      } \
      __builtin_amdgcn_s_setprio(0); \
    }

  // TILE: loads/stages for the future, compute current, counted gate.
#define TILE(bu, t, bcur, bnxt) { \
    if ((t) + 1 < NT) LOADB(bnxt, (t) + 1) \
    if ((t) + 2 < NT) STAGE_A(((t) + 2) % 3, (t) + 2) \
    COMPUTE(bu, bcur) \
    if ((t) < NT - 2) { \
      asm volatile("s_waitcnt vmcnt(4)" ::: "memory"); \
      __builtin_amdgcn_s_barrier(); \
    } else if ((t) == NT - 2) { \
      asm volatile("s_waitcnt vmcnt(0)" ::: "memory"); \
      __builtin_amdgcn_s_barrier(); \
    } \
  }

  // Prologue: A(0),A(1) staged; B(0) in regs; full drain; publish.
  STAGE_A(0, 0)
  STAGE_A(1, 1)
  LOADB(bcA, 0)
  asm volatile("s_waitcnt vmcnt(0)" ::: "memory");
  __builtin_amdgcn_s_barrier();
  __builtin_amdgcn_sched_barrier(0);

  // 96 tiles = 16 x 6 (lcm of buf period 3 and reg ping-pong 2)
  for (int i = 0; i < 16; ++i) {
    const int t = i * 6;
    TILE(0, t + 0, bcA, bcB)
    TILE(1, t + 1, bcB, bcA)
    TILE(2, t + 2, bcA, bcB)
    TILE(0, t + 3, bcB, bcA)
    TILE(1, t + 4, bcA, bcB)
    TILE(2, t + 5, bcB, bcA)
  }

  // Epilogue (R9/R12-validated): col=lane&15, row=(lane>>4)*4+reg
  const int colLane = lane & 15;
  const int rowGrp  = (lane >> 4) * 4;
#pragma unroll
  for (int fn = 0; fn < 4; ++fn) {
    const int col = bn * 256 + wn * 64 + fn * 16 + colLane;
    if (col < NREAL) {
      const float bias = fb[col] + bb[col] + lb[col];
#pragma unroll
      for (int fm = 0; fm < 8; ++fm) {
        const int row0 = bm * 256 + wm * 128 + fm * 16 + rowGrp;
#pragma unroll
        for (int r = 0; r < 4; ++r) {
          const float pre = acc[fm][fn][r] + bias;
          const size_t oi = (size_t)(row0 + r) * NREAL + col;
          out[oi] = 0.7f * fmaxf(pre, 0.f) + 0.3f * selfact[oi];
        }
      }
    }
  }
#undef TILE
#undef COMPUTE
#undef LOADB
#undef STAGE_A
#undef STQ
}

// ---------------------------------------------------------------------------
extern "C" void kernel_launch(void* const* d_in, const int* in_sizes, int n_in,
                              void* d_out, int out_size, void* d_ws,
                              size_t ws_size, hipStream_t stream) {
  const float* prev = (const float*)d_in[0];
  const float* selfa = (const float*)d_in[1];
  const float* nxt  = (const float*)d_in[2];
  const float* fW = (const float*)d_in[3];
  const float* fb = (const float*)d_in[4];
  const float* bW = (const float*)d_in[5];
  const float* bb = (const float*)d_in[6];
  const float* lW = (const float*)d_in[7];
  const float* lb = (const float*)d_in[8];
  float* out = (float*)d_out;

  unsigned short* Acat = (unsigned short*)d_ws;                 // 100.7 MB
  unsigned short* Wfr  = Acat + (size_t)BATCH * KPAD;           // +25.2 MB

  apack_kernel<<<dim3(BATCH, 3), 256, 0, stream>>>(prev, nxt, selfa, Acat);
  wfrag_kernel<<<dim3(128, 3), 256, 0, stream>>>(fW, bW, lW, Wfr);
  gemm_kernel<<<dim3(32 * 8), 512, 0, stream>>>(Acat, Wfr, fb, bb, lb,
                                                selfa, out);
}

// Round 14
// 256.728 us; speedup vs baseline: 2.2418x; 2.2418x over previous
//
#include <hip/hip_runtime.h>
#include <hip/hip_bf16.h>

// Sizes
constexpr int BATCH = 8192;
constexpr int NREAL = 2000;   // real feature / output-col count
constexpr int KSLOT = 2048;   // per-matrix padded K slot
constexpr int KPAD  = 6144;   // 3 * 2048
constexpr int NPAD  = 2048;   // padded N (W_cat rows)
constexpr int NT    = KPAD / 64;  // 96 K-tiles of 64

typedef short bf16x8 __attribute__((ext_vector_type(8)));
typedef float f32x4  __attribute__((ext_vector_type(4)));

__device__ inline void gload_lds16(const void* g, void* l) {
  __builtin_amdgcn_global_load_lds(
      (const __attribute__((address_space(1))) unsigned int*)g,
      (__attribute__((address_space(3))) unsigned int*)l,
      16, 0, 0);
}

__device__ inline unsigned short f2bf(float x) {
  union { float f; unsigned int u; } v;
  v.f = x;
  unsigned int r = v.u + 0x7fffu + ((v.u >> 16) & 1u);
  return (unsigned short)(r >> 16);
}

// ---------------------------------------------------------------------------
// Kernel 1: fused pack. blockIdx.x < 8192: standardize (ddof=1) activations
// into A_cat [8192][6144]; else weight-concat rows into W_cat [2048][6144].
// grid (8192+2048, 3), block 256.
// ---------------------------------------------------------------------------
__global__ __launch_bounds__(256) void pack_kernel(
    const float* __restrict__ prev, const float* __restrict__ nxt,
    const float* __restrict__ selfa,
    const float* __restrict__ fW, const float* __restrict__ bW,
    const float* __restrict__ lW,
    unsigned short* __restrict__ Acat, unsigned short* __restrict__ Wcat) {
  const int mat = blockIdx.y;
  const int t = threadIdx.x;

  if (blockIdx.x >= BATCH) {
    // ---- weight pack ----
    const int s = blockIdx.x - BATCH;
    uint4 q = make_uint4(0, 0, 0, 0);
    if (s < NREAL && t < 250) {
      const float* src = ((mat == 0) ? fW : (mat == 1) ? bW : lW) +
                         (size_t)s * NREAL + t * 8;
      const float4* p = (const float4*)src;
      float4 a = p[0], b = p[1];
      q.x = (unsigned)f2bf(a.x) | ((unsigned)f2bf(a.y) << 16);
      q.y = (unsigned)f2bf(a.z) | ((unsigned)f2bf(a.w) << 16);
      q.z = (unsigned)f2bf(b.x) | ((unsigned)f2bf(b.y) << 16);
      q.w = (unsigned)f2bf(b.z) | ((unsigned)f2bf(b.w) << 16);
    }
    *(uint4*)(Wcat + (size_t)s * KPAD + mat * KSLOT + t * 8) = q;
    return;
  }

  // ---- standardize pack ----
  __shared__ float red[4];
  const int row = blockIdx.x;
  const float* src = (mat == 0) ? prev : (mat == 1) ? nxt : selfa;

  float x[8];
  float s1 = 0.f;
  if (t < 250) {
    const float4* p = (const float4*)(src + (size_t)row * NREAL + t * 8);
    float4 a = p[0], b = p[1];
    x[0] = a.x; x[1] = a.y; x[2] = a.z; x[3] = a.w;
    x[4] = b.x; x[5] = b.y; x[6] = b.z; x[7] = b.w;
#pragma unroll
    for (int j = 0; j < 8; ++j) s1 += x[j];
  } else {
#pragma unroll
    for (int j = 0; j < 8; ++j) x[j] = 0.f;
  }
#pragma unroll
  for (int o = 32; o; o >>= 1) s1 += __shfl_xor(s1, o);
  if ((t & 63) == 0) red[t >> 6] = s1;
  __syncthreads();
  const float mean = (red[0] + red[1] + red[2] + red[3]) * (1.f / 2000.f);
  __syncthreads();

  float ss = 0.f;
  if (t < 250) {
#pragma unroll
    for (int j = 0; j < 8; ++j) { float d = x[j] - mean; ss += d * d; }
  }
#pragma unroll
  for (int o = 32; o; o >>= 1) ss += __shfl_xor(ss, o);
  if ((t & 63) == 0) red[t >> 6] = ss;
  __syncthreads();
  const float var = (red[0] + red[1] + red[2] + red[3]) * (1.f / 1999.f);
  const float scale = 1.f / (sqrtf(var) + 1e-8f);

  unsigned short o8[8];
  if (t < 250) {
#pragma unroll
    for (int j = 0; j < 8; ++j) o8[j] = f2bf((x[j] - mean) * scale);
  } else {
#pragma unroll
    for (int j = 0; j < 8; ++j) o8[j] = 0;
  }
  uint4 q;
  q.x = (unsigned)o8[0] | ((unsigned)o8[1] << 16);
  q.y = (unsigned)o8[2] | ((unsigned)o8[3] << 16);
  q.z = (unsigned)o8[4] | ((unsigned)o8[5] << 16);
  q.w = (unsigned)o8[6] | ((unsigned)o8[7] << 16);
  *(uint4*)(Acat + (size_t)row * KPAD + mat * KSLOT + t * 8) = q;
}

// ---------------------------------------------------------------------------
// Kernel 2: R9 configuration (session-best, 216 us GEMM / 954 TF).
// 8-phase m201-style: 256x256, BK=64, 8 waves (2M x 4N), 128x64/wave.
// Per phase: {4 af ds_reads (+8 bf at ph0) -> stage one row-half (2 gloads)
// -> [lgkmcnt(8) at ph0] -> barrier -> lgkmcnt(0) -> setprio(1) -> 16 MFMA
// -> setprio(0) -> [vmcnt(4) gate at ph3 only] -> barrier}. B read ONCE
// per tile (32 VGPR). Stage plan: A(t+1) at ph0/ph1, B(t+2) at ph2/ph3 ->
// FIFO at gate = [B(t+1)x4, A(t+1)x4, B(t+2)x4]; vmcnt(4) forces exactly
// t+1's data (issued 2-5 phases back). LDS [buf][mat][kq][256][32], proven
// 0-conflict XOR swizzle. grid 256 (= 32 bm x 8 bn), block 512.
// ---------------------------------------------------------------------------
__global__ __launch_bounds__(512, 2) void gemm_kernel(
    const unsigned short* __restrict__ A,   // [8192][6144] bf16
    const unsigned short* __restrict__ W,   // [2048][6144] bf16
    const float* __restrict__ fb, const float* __restrict__ bb,
    const float* __restrict__ lb,
    const float* __restrict__ selfact,      // [8192][2000] f32
    float* __restrict__ out) {              // [8192][2000] f32
  __shared__ unsigned short ldsS[2][2][2][256][32];  // 128 KiB
  unsigned short* ldsF = &ldsS[0][0][0][0][0];

  const int tid  = threadIdx.x;
  const int wave = tid >> 6;
  const int lane = tid & 63;
  const int wm = wave >> 2;     // 0..1
  const int wn = wave & 3;      // 0..3

  // XCD-aware block swizzle (256 blocks, 8 XCDs, 32/XCD, 4 bm-panels each)
  const int nbid = (blockIdx.x & 7) * 32 + (blockIdx.x >> 3);
  const int bm = nbid >> 3;     // 0..31
  const int bn = nbid & 7;      // 0..7

  // staging per-thread source (inverse swizzle): srow=tid>>2 (row within
  // a row-half), chunk sc = (tid&3) ^ ((srow>>1)&3)
  const int srow = tid >> 2;
  const int sc = (tid & 3) ^ ((tid >> 3) & 3);
  const unsigned short* Asrc =
      A + (size_t)(bm * 256 + srow) * KPAD + sc * 8;
  const unsigned short* Bsrc =
      W + (size_t)(bn * 256 + srow) * KPAD + sc * 8;

  // fragment read bases (swizzle folds to per-lane constant)
  const int pcx = (lane >> 4) ^ ((lane >> 1) & 3);
  const unsigned short* aF = ldsF + (wm * 128 + (lane & 15)) * 32 + pcx * 8;
  const unsigned short* bF = ldsF + (wn * 64 + (lane & 15)) * 32 + pcx * 8;

  f32x4 acc[8][4] = {};
  bf16x8 bfr[4][2];

  // stage one kk-quarter of one row-half: (buf, mat, kq, rh) of tile tt
#define STQ(bu, mat, kq, rh, tt) { \
    const unsigned short* g_ = ((mat) ? Bsrc : Asrc) + \
        (size_t)(rh) * 128 * KPAD + (size_t)(tt) * 64 + (kq) * 32; \
    unsigned short* d_ = ldsF + ((bu) * 4 + (mat) * 2 + (kq)) * 8192 + \
        (rh) * 4096 + wave * 512; \
    gload_lds16(g_, d_); \
  }

#define READ_BF(bu) \
    _Pragma("unroll") for (int fn = 0; fn < 4; ++fn) \
    _Pragma("unroll") for (int kk = 0; kk < 2; ++kk) \
      bfr[fn][kk] = *(const bf16x8*)(bF + ((bu) * 4 + 2 + kk) * 8192 + fn * 512);

  // one phase: quadrant p (rows 2p*16..2p*16+31 of the wave's half)
#define PHASE(bu, p, STG, GATE) { \
    bf16x8 a00 = *(const bf16x8*)(aF + ((bu) * 4 + 0) * 8192 + (2 * (p)) * 512); \
    bf16x8 a01 = *(const bf16x8*)(aF + ((bu) * 4 + 1) * 8192 + (2 * (p)) * 512); \
    bf16x8 a10 = *(const bf16x8*)(aF + ((bu) * 4 + 0) * 8192 + (2 * (p) + 1) * 512); \
    bf16x8 a11 = *(const bf16x8*)(aF + ((bu) * 4 + 1) * 8192 + (2 * (p) + 1) * 512); \
    if ((p) == 0) { READ_BF(bu) } \
    STG \
    if ((p) == 0) asm volatile("s_waitcnt lgkmcnt(8)" ::: "memory"); \
    __builtin_amdgcn_s_barrier(); \
    asm volatile("s_waitcnt lgkmcnt(0)" ::: "memory"); \
    __builtin_amdgcn_s_setprio(1); \
    _Pragma("unroll") for (int fn = 0; fn < 4; ++fn) { \
      acc[2 * (p)][fn] = __builtin_amdgcn_mfma_f32_16x16x32_bf16( \
          a00, bfr[fn][0], acc[2 * (p)][fn], 0, 0, 0); \
      acc[2 * (p)][fn] = __builtin_amdgcn_mfma_f32_16x16x32_bf16( \
          a01, bfr[fn][1], acc[2 * (p)][fn], 0, 0, 0); \
      acc[2 * (p) + 1][fn] = __builtin_amdgcn_mfma_f32_16x16x32_bf16( \
          a10, bfr[fn][0], acc[2 * (p) + 1][fn], 0, 0, 0); \
      acc[2 * (p) + 1][fn] = __builtin_amdgcn_mfma_f32_16x16x32_bf16( \
          a11, bfr[fn][1], acc[2 * (p) + 1][fn], 0, 0, 0); \
    } \
    __builtin_amdgcn_s_setprio(0); \
    GATE \
    __builtin_amdgcn_s_barrier(); \
  }

  // TILE(t, bu): SA = stage A(t+1), SB = stage B(t+2), gate string at ph3
#define TILE(bu, t, SA, SB, GATE) { \
    PHASE(bu, 0, if (SA) { STQ((bu) ^ 1, 0, 0, 0, (t) + 1) STQ((bu) ^ 1, 0, 1, 0, (t) + 1) }, ) \
    PHASE(bu, 1, if (SA) { STQ((bu) ^ 1, 0, 0, 1, (t) + 1) STQ((bu) ^ 1, 0, 1, 1, (t) + 1) }, ) \
    PHASE(bu, 2, if (SB) { STQ((bu), 1, 0, 0, (t) + 2) STQ((bu), 1, 1, 0, (t) + 2) }, ) \
    PHASE(bu, 3, if (SB) { STQ((bu), 1, 0, 1, (t) + 2) STQ((bu), 1, 1, 1, (t) + 2) }, GATE) \
  }

  // Prologue: A(0), B(0) -> buf0; B(1) -> buf1. 12 loads/wave.
  STQ(0, 0, 0, 0, 0) STQ(0, 0, 1, 0, 0)   // A0 rh0
  STQ(0, 0, 0, 1, 0) STQ(0, 0, 1, 1, 0)   // A0 rh1
  STQ(0, 1, 0, 0, 0) STQ(0, 1, 1, 0, 0)   // B0 rh0
  STQ(0, 1, 0, 1, 0) STQ(0, 1, 1, 1, 0)   // B0 rh1
  STQ(1, 1, 0, 0, 1) STQ(1, 1, 1, 0, 1)   // B1 rh0
  STQ(1, 1, 0, 1, 1) STQ(1, 1, 1, 1, 1)   // B1 rh1
  asm volatile("s_waitcnt vmcnt(4)" ::: "memory");   // A0+B0 landed
  __builtin_amdgcn_s_barrier();

  for (int i = 0; i < 47; ++i) {
    const int t = 2 * i;
    TILE(0, t, true, true,
         asm volatile("s_waitcnt vmcnt(4)" ::: "memory");)
    TILE(1, t + 1, true, true,
         asm volatile("s_waitcnt vmcnt(4)" ::: "memory");)
  }
  // t = 94: stage A(95) only; drain all (forces A95+B95).
  TILE(0, 94, true, false,
       asm volatile("s_waitcnt vmcnt(0)" ::: "memory");)
  // t = 95: nothing staged, no gate.
  TILE(1, 95, false, false, )

  // Epilogue: C/D layout col=lane&15, row=(lane>>4)*4+reg
  const int colLane = lane & 15;
  const int rowGrp  = (lane >> 4) * 4;
#pragma unroll
  for (int fn = 0; fn < 4; ++fn) {
    const int col = bn * 256 + wn * 64 + fn * 16 + colLane;
    if (col < NREAL) {
      const float bias = fb[col] + bb[col] + lb[col];
#pragma unroll
      for (int fm = 0; fm < 8; ++fm) {
        const int row0 = bm * 256 + wm * 128 + fm * 16 + rowGrp;
#pragma unroll
        for (int r = 0; r < 4; ++r) {
          const float pre = acc[fm][fn][r] + bias;
          const size_t oi = (size_t)(row0 + r) * NREAL + col;
          out[oi] = 0.7f * fmaxf(pre, 0.f) + 0.3f * selfact[oi];
        }
      }
    }
  }
#undef TILE
#undef PHASE
#undef READ_BF
#undef STQ
}

// ---------------------------------------------------------------------------
extern "C" void kernel_launch(void* const* d_in, const int* in_sizes, int n_in,
                              void* d_out, int out_size, void* d_ws,
                              size_t ws_size, hipStream_t stream) {
  const float* prev = (const float*)d_in[0];
  const float* selfa = (const float*)d_in[1];
  const float* nxt  = (const float*)d_in[2];
  const float* fW = (const float*)d_in[3];
  const float* fb = (const float*)d_in[4];
  const float* bW = (const float*)d_in[5];
  const float* bb = (const float*)d_in[6];
  const float* lW = (const float*)d_in[7];
  const float* lb = (const float*)d_in[8];
  float* out = (float*)d_out;

  unsigned short* Acat = (unsigned short*)d_ws;                 // 100.7 MB
  unsigned short* Wcat = Acat + (size_t)BATCH * KPAD;           // +25.2 MB

  pack_kernel<<<dim3(BATCH + NPAD, 3), 256, 0, stream>>>(
      prev, nxt, selfa, fW, bW, lW, Acat, Wcat);
  gemm_kernel<<<dim3(32 * 8), 512, 0, stream>>>(Acat, Wcat, fb, bb, lb,
                                                selfa, out);
}

// Round 15
// 250.954 us; speedup vs baseline: 2.2934x; 1.0230x over previous
//
#include <hip/hip_runtime.h>
#include <hip/hip_bf16.h>

// Sizes
constexpr int BATCH = 8192;
constexpr int NREAL = 2000;   // real feature / output-col count
constexpr int KPAD  = 6016;   // 3*2000 + 16 pad = 94 * 64 (tight K packing)
constexpr int NPAD  = 2048;   // padded N (W_cat rows)
constexpr int NT    = KPAD / 64;  // 94 K-tiles of 64

typedef short bf16x8 __attribute__((ext_vector_type(8)));
typedef float f32x4  __attribute__((ext_vector_type(4)));

__device__ inline void gload_lds16(const void* g, void* l) {
  __builtin_amdgcn_global_load_lds(
      (const __attribute__((address_space(1))) unsigned int*)g,
      (__attribute__((address_space(3))) unsigned int*)l,
      16, 0, 0);
}

__device__ inline unsigned short f2bf(float x) {
  union { float f; unsigned int u; } v;
  v.f = x;
  unsigned int r = v.u + 0x7fffu + ((v.u >> 16) & 1u);
  return (unsigned short)(r >> 16);
}

// ---------------------------------------------------------------------------
// Kernel 1: fused pack. blockIdx.x < 8192: standardize (ddof=1) activations
// into A_cat [8192][6016]; else weight-concat rows into W_cat [2048][6016].
// Row layout: [prev 2000 | next 2000 | self 2000 | 16-short zero pad].
// grid (8192+2048, 3), block 256. mat==2 threads 250/251 zero the row tail.
// ---------------------------------------------------------------------------
__global__ __launch_bounds__(256) void pack_kernel(
    const float* __restrict__ prev, const float* __restrict__ nxt,
    const float* __restrict__ selfa,
    const float* __restrict__ fW, const float* __restrict__ bW,
    const float* __restrict__ lW,
    unsigned short* __restrict__ Acat, unsigned short* __restrict__ Wcat) {
  const int mat = blockIdx.y;
  const int t = threadIdx.x;

  if (blockIdx.x >= BATCH) {
    // ---- weight pack ----
    const int s = blockIdx.x - BATCH;
    if (t < 250) {
      uint4 q = make_uint4(0, 0, 0, 0);
      if (s < NREAL) {
        const float* src = ((mat == 0) ? fW : (mat == 1) ? bW : lW) +
                           (size_t)s * NREAL + t * 8;
        const float4* p = (const float4*)src;
        float4 a = p[0], b = p[1];
        q.x = (unsigned)f2bf(a.x) | ((unsigned)f2bf(a.y) << 16);
        q.y = (unsigned)f2bf(a.z) | ((unsigned)f2bf(a.w) << 16);
        q.z = (unsigned)f2bf(b.x) | ((unsigned)f2bf(b.y) << 16);
        q.w = (unsigned)f2bf(b.z) | ((unsigned)f2bf(b.w) << 16);
      }
      *(uint4*)(Wcat + (size_t)s * KPAD + mat * NREAL + t * 8) = q;
    } else if (mat == 2 && t < 252) {
      // zero the 16-short row tail [6000..6016)
      *(uint4*)(Wcat + (size_t)s * KPAD + 6000 + (t - 250) * 8) =
          make_uint4(0, 0, 0, 0);
    }
    return;
  }

  // ---- standardize pack ----
  __shared__ float red[4];
  const int row = blockIdx.x;
  const float* src = (mat == 0) ? prev : (mat == 1) ? nxt : selfa;

  float x[8];
  float s1 = 0.f;
  if (t < 250) {
    const float4* p = (const float4*)(src + (size_t)row * NREAL + t * 8);
    float4 a = p[0], b = p[1];
    x[0] = a.x; x[1] = a.y; x[2] = a.z; x[3] = a.w;
    x[4] = b.x; x[5] = b.y; x[6] = b.z; x[7] = b.w;
#pragma unroll
    for (int j = 0; j < 8; ++j) s1 += x[j];
  } else {
#pragma unroll
    for (int j = 0; j < 8; ++j) x[j] = 0.f;
  }
#pragma unroll
  for (int o = 32; o; o >>= 1) s1 += __shfl_xor(s1, o);
  if ((t & 63) == 0) red[t >> 6] = s1;
  __syncthreads();
  const float mean = (red[0] + red[1] + red[2] + red[3]) * (1.f / 2000.f);
  __syncthreads();

  float ss = 0.f;
  if (t < 250) {
#pragma unroll
    for (int j = 0; j < 8; ++j) { float d = x[j] - mean; ss += d * d; }
  }
#pragma unroll
  for (int o = 32; o; o >>= 1) ss += __shfl_xor(ss, o);
  if ((t & 63) == 0) red[t >> 6] = ss;
  __syncthreads();
  const float var = (red[0] + red[1] + red[2] + red[3]) * (1.f / 1999.f);
  const float scale = 1.f / (sqrtf(var) + 1e-8f);

  if (t < 250) {
    unsigned short o8[8];
#pragma unroll
    for (int j = 0; j < 8; ++j) o8[j] = f2bf((x[j] - mean) * scale);
    uint4 q;
    q.x = (unsigned)o8[0] | ((unsigned)o8[1] << 16);
    q.y = (unsigned)o8[2] | ((unsigned)o8[3] << 16);
    q.z = (unsigned)o8[4] | ((unsigned)o8[5] << 16);
    q.w = (unsigned)o8[6] | ((unsigned)o8[7] << 16);
    *(uint4*)(Acat + (size_t)row * KPAD + mat * NREAL + t * 8) = q;
  } else if (mat == 2 && t < 252) {
    *(uint4*)(Acat + (size_t)row * KPAD + 6000 + (t - 250) * 8) =
        make_uint4(0, 0, 0, 0);
  }
}

// ---------------------------------------------------------------------------
// Kernel 2: session-best R9 configuration + tight K (NT=94).
// 8-phase m201-style: 256x256, BK=64, 8 waves (2M x 4N), 128x64/wave.
// Per phase: {4 af ds_reads (+8 bf at ph0) -> stage one row-half (2 gloads)
// -> [lgkmcnt(8) at ph0] -> barrier -> lgkmcnt(0) -> setprio(1) -> 16 MFMA
// -> setprio(0) -> [vmcnt(4) gate at ph3 only] -> barrier}. B read ONCE
// per tile (32 VGPR). Stage plan: A(t+1) at ph0/ph1, B(t+2) at ph2/ph3 ->
// FIFO at gate = [B(t+1)x4, A(t+1)x4, B(t+2)x4]; vmcnt(4) forces exactly
// t+1's data (issued 2-5 phases back). LDS [buf][mat][kq][256][32], proven
// 0-conflict XOR swizzle. grid 256 (= 32 bm x 8 bn), block 512.
// ---------------------------------------------------------------------------
__global__ __launch_bounds__(512, 2) void gemm_kernel(
    const unsigned short* __restrict__ A,   // [8192][6016] bf16
    const unsigned short* __restrict__ W,   // [2048][6016] bf16
    const float* __restrict__ fb, const float* __restrict__ bb,
    const float* __restrict__ lb,
    const float* __restrict__ selfact,      // [8192][2000] f32
    float* __restrict__ out) {              // [8192][2000] f32
  __shared__ unsigned short ldsS[2][2][2][256][32];  // 128 KiB
  unsigned short* ldsF = &ldsS[0][0][0][0][0];

  const int tid  = threadIdx.x;
  const int wave = tid >> 6;
  const int lane = tid & 63;
  const int wm = wave >> 2;     // 0..1
  const int wn = wave & 3;      // 0..3

  // XCD-aware block swizzle (256 blocks, 8 XCDs, 32/XCD, 4 bm-panels each)
  const int nbid = (blockIdx.x & 7) * 32 + (blockIdx.x >> 3);
  const int bm = nbid >> 3;     // 0..31
  const int bn = nbid & 7;      // 0..7

  // staging per-thread source (inverse swizzle): srow=tid>>2 (row within
  // a row-half), chunk sc = (tid&3) ^ ((srow>>1)&3)
  const int srow = tid >> 2;
  const int sc = (tid & 3) ^ ((tid >> 3) & 3);
  const unsigned short* Asrc =
      A + (size_t)(bm * 256 + srow) * KPAD + sc * 8;
  const unsigned short* Bsrc =
      W + (size_t)(bn * 256 + srow) * KPAD + sc * 8;

  // fragment read bases (swizzle folds to per-lane constant)
  const int pcx = (lane >> 4) ^ ((lane >> 1) & 3);
  const unsigned short* aF = ldsF + (wm * 128 + (lane & 15)) * 32 + pcx * 8;
  const unsigned short* bF = ldsF + (wn * 64 + (lane & 15)) * 32 + pcx * 8;

  f32x4 acc[8][4] = {};
  bf16x8 bfr[4][2];

  // stage one kk-quarter of one row-half: (buf, mat, kq, rh) of tile tt
#define STQ(bu, mat, kq, rh, tt) { \
    const unsigned short* g_ = ((mat) ? Bsrc : Asrc) + \
        (size_t)(rh) * 128 * KPAD + (size_t)(tt) * 64 + (kq) * 32; \
    unsigned short* d_ = ldsF + ((bu) * 4 + (mat) * 2 + (kq)) * 8192 + \
        (rh) * 4096 + wave * 512; \
    gload_lds16(g_, d_); \
  }

#define READ_BF(bu) \
    _Pragma("unroll") for (int fn = 0; fn < 4; ++fn) \
    _Pragma("unroll") for (int kk = 0; kk < 2; ++kk) \
      bfr[fn][kk] = *(const bf16x8*)(bF + ((bu) * 4 + 2 + kk) * 8192 + fn * 512);

  // one phase: quadrant p (rows 2p*16..2p*16+31 of the wave's half)
#define PHASE(bu, p, STG, GATE) { \
    bf16x8 a00 = *(const bf16x8*)(aF + ((bu) * 4 + 0) * 8192 + (2 * (p)) * 512); \
    bf16x8 a01 = *(const bf16x8*)(aF + ((bu) * 4 + 1) * 8192 + (2 * (p)) * 512); \
    bf16x8 a10 = *(const bf16x8*)(aF + ((bu) * 4 + 0) * 8192 + (2 * (p) + 1) * 512); \
    bf16x8 a11 = *(const bf16x8*)(aF + ((bu) * 4 + 1) * 8192 + (2 * (p) + 1) * 512); \
    if ((p) == 0) { READ_BF(bu) } \
    STG \
    if ((p) == 0) asm volatile("s_waitcnt lgkmcnt(8)" ::: "memory"); \
    __builtin_amdgcn_s_barrier(); \
    asm volatile("s_waitcnt lgkmcnt(0)" ::: "memory"); \
    __builtin_amdgcn_s_setprio(1); \
    _Pragma("unroll") for (int fn = 0; fn < 4; ++fn) { \
      acc[2 * (p)][fn] = __builtin_amdgcn_mfma_f32_16x16x32_bf16( \
          a00, bfr[fn][0], acc[2 * (p)][fn], 0, 0, 0); \
      acc[2 * (p)][fn] = __builtin_amdgcn_mfma_f32_16x16x32_bf16( \
          a01, bfr[fn][1], acc[2 * (p)][fn], 0, 0, 0); \
      acc[2 * (p) + 1][fn] = __builtin_amdgcn_mfma_f32_16x16x32_bf16( \
          a10, bfr[fn][0], acc[2 * (p) + 1][fn], 0, 0, 0); \
      acc[2 * (p) + 1][fn] = __builtin_amdgcn_mfma_f32_16x16x32_bf16( \
          a11, bfr[fn][1], acc[2 * (p) + 1][fn], 0, 0, 0); \
    } \
    __builtin_amdgcn_s_setprio(0); \
    GATE \
    __builtin_amdgcn_s_barrier(); \
  }

  // TILE(t, bu): SA = stage A(t+1), SB = stage B(t+2), gate string at ph3
#define TILE(bu, t, SA, SB, GATE) { \
    PHASE(bu, 0, if (SA) { STQ((bu) ^ 1, 0, 0, 0, (t) + 1) STQ((bu) ^ 1, 0, 1, 0, (t) + 1) }, ) \
    PHASE(bu, 1, if (SA) { STQ((bu) ^ 1, 0, 0, 1, (t) + 1) STQ((bu) ^ 1, 0, 1, 1, (t) + 1) }, ) \
    PHASE(bu, 2, if (SB) { STQ((bu), 1, 0, 0, (t) + 2) STQ((bu), 1, 1, 0, (t) + 2) }, ) \
    PHASE(bu, 3, if (SB) { STQ((bu), 1, 0, 1, (t) + 2) STQ((bu), 1, 1, 1, (t) + 2) }, GATE) \
  }

  // Prologue: A(0), B(0) -> buf0; B(1) -> buf1. 12 loads/wave.
  STQ(0, 0, 0, 0, 0) STQ(0, 0, 1, 0, 0)   // A0 rh0
  STQ(0, 0, 0, 1, 0) STQ(0, 0, 1, 1, 0)   // A0 rh1
  STQ(0, 1, 0, 0, 0) STQ(0, 1, 1, 0, 0)   // B0 rh0
  STQ(0, 1, 0, 1, 0) STQ(0, 1, 1, 1, 0)   // B0 rh1
  STQ(1, 1, 0, 0, 1) STQ(1, 1, 1, 0, 1)   // B1 rh0
  STQ(1, 1, 0, 1, 1) STQ(1, 1, 1, 1, 1)   // B1 rh1
  asm volatile("s_waitcnt vmcnt(4)" ::: "memory");   // A0+B0 landed
  __builtin_amdgcn_s_barrier();

  // NT = 94 tiles: 46 double-tiles full steady state, then t=92/93 tail.
  for (int i = 0; i < 46; ++i) {
    const int t = 2 * i;
    TILE(0, t, true, true,
         asm volatile("s_waitcnt vmcnt(4)" ::: "memory");)
    TILE(1, t + 1, true, true,
         asm volatile("s_waitcnt vmcnt(4)" ::: "memory");)
  }
  // t = 92: stage A(93) only; drain all (forces A93+B93).
  TILE(0, 92, true, false,
       asm volatile("s_waitcnt vmcnt(0)" ::: "memory");)
  // t = 93: nothing staged, no gate.
  TILE(1, 93, false, false, )

  // Epilogue: C/D layout col=lane&15, row=(lane>>4)*4+reg
  const int colLane = lane & 15;
  const int rowGrp  = (lane >> 4) * 4;
#pragma unroll
  for (int fn = 0; fn < 4; ++fn) {
    const int col = bn * 256 + wn * 64 + fn * 16 + colLane;
    if (col < NREAL) {
      const float bias = fb[col] + bb[col] + lb[col];
#pragma unroll
      for (int fm = 0; fm < 8; ++fm) {
        const int row0 = bm * 256 + wm * 128 + fm * 16 + rowGrp;
#pragma unroll
        for (int r = 0; r < 4; ++r) {
          const float pre = acc[fm][fn][r] + bias;
          const size_t oi = (size_t)(row0 + r) * NREAL + col;
          out[oi] = 0.7f * fmaxf(pre, 0.f) + 0.3f * selfact[oi];
        }
      }
    }
  }
#undef TILE
#undef PHASE
#undef READ_BF
#undef STQ
}

// ---------------------------------------------------------------------------
extern "C" void kernel_launch(void* const* d_in, const int* in_sizes, int n_in,
                              void* d_out, int out_size, void* d_ws,
                              size_t ws_size, hipStream_t stream) {
  const float* prev = (const float*)d_in[0];
  const float* selfa = (const float*)d_in[1];
  const float* nxt  = (const float*)d_in[2];
  const float* fW = (const float*)d_in[3];
  const float* fb = (const float*)d_in[4];
  const float* bW = (const float*)d_in[5];
  const float* bb = (const float*)d_in[6];
  const float* lW = (const float*)d_in[7];
  const float* lb = (const float*)d_in[8];
  float* out = (float*)d_out;

  unsigned short* Acat = (unsigned short*)d_ws;                 // 98.6 MB
  unsigned short* Wcat = Acat + (size_t)BATCH * KPAD;           // +24.6 MB

  pack_kernel<<<dim3(BATCH + NPAD, 3), 256, 0, stream>>>(
      prev, nxt, selfa, fW, bW, lW, Acat, Wcat);
  gemm_kernel<<<dim3(32 * 8), 512, 0, stream>>>(Acat, Wcat, fb, bb, lb,
                                                selfa, out);
}